// Round 4
// baseline (431.881 us; speedup 1.0000x reference)
//
#include <hip/hip_runtime.h>
#include <math.h>

#define Bq 2
#define Lq 2048
#define DIMq 768
#define NHq 12
#define HDq 64

typedef __attribute__((ext_vector_type(8))) short short8;
typedef __attribute__((ext_vector_type(4))) short short4v;
typedef __attribute__((ext_vector_type(4))) float float4v;

// async global->LDS, 16 B per lane; LDS dest = wave-uniform base + lane*16
#define GL2LDS(g, l) __builtin_amdgcn_global_load_lds( \
    (const __attribute__((address_space(1))) unsigned int*)(g), \
    (__attribute__((address_space(3))) unsigned int*)(l), 16, 0, 0)

static __device__ __forceinline__ short f2bf(float f) {
    union { float f; unsigned u; } v; v.f = f;
    unsigned r = (v.u + 0x7FFF + ((v.u >> 16) & 1)) >> 16;   // RNE
    return (short)r;
}

// ---------------------------------------------------------------------------
// fp32 -> bf16 for x and the four weights (wq/wk/wv written contiguously).
// ---------------------------------------------------------------------------
__global__ __launch_bounds__(256)
void to_bf16(const float* __restrict__ x,  const float* __restrict__ wq,
             const float* __restrict__ wk, const float* __restrict__ wv,
             const float* __restrict__ wo,
             short* __restrict__ xb, short* __restrict__ wqb,
             short* __restrict__ wkb, short* __restrict__ wvb,
             short* __restrict__ wob)
{
    int blk = blockIdx.x;
    const float* s; short* d; int off;
    if      (blk <  768) { s = x;  d = xb;  off = blk * 1024; }
    else if (blk <  912) { s = wq; d = wqb; off = (blk -  768) * 1024; }
    else if (blk < 1056) { s = wk; d = wkb; off = (blk -  912) * 1024; }
    else if (blk < 1200) { s = wv; d = wvb; off = (blk - 1056) * 1024; }
    else                 { s = wo; d = wob; off = (blk - 1200) * 1024; }
    const float4* s4 = (const float4*)s;
    short4v* d4 = (short4v*)d;
#pragma unroll
    for (int i = 0; i < 4; ++i) {
        int idx = off + threadIdx.x + i * 256;
        float4 v = s4[idx];
        short4v o;
        o[0] = f2bf(v.x); o[1] = f2bf(v.y); o[2] = f2bf(v.z); o[3] = f2bf(v.w);
        d4[idx] = o;
    }
}

// ---------------------------------------------------------------------------
// m97-style bf16 GEMM: C = A @ W^T.  128x128 tile, BK=64, 4 waves (2x2 of
// 64x64), global_load_lds(16B) staging, XOR chunk swizzle (no padding
// possible with lds-direct loads; swizzle makes b128 frag reads 2-way = free).
// LDS slot chunk s of row r holds global chunk s^(r&7).
// mode 0: OutF fp32 [M][768].
// mode 1: N=2304 fused QKV; writes Qg [bh][l][hd] bf16, Ktg/Vtg pre-tiled
//         pre-swizzled bf16 tiles that are exact LDS images for attention.
// ---------------------------------------------------------------------------
__global__ __launch_bounds__(256, 2)
void gemm128(const short* __restrict__ A, const short* __restrict__ W,
             short* __restrict__ Qg, short* __restrict__ Ktg,
             short* __restrict__ Vtg, float* __restrict__ OutF, int mode)
{
    __shared__ __align__(16) short As[128 * 64];
    __shared__ __align__(16) short Bs[128 * 64];
    const int tid = threadIdx.x;
    const int wave = tid >> 6, lane = tid & 63;
    const int col = lane & 15, quad = lane >> 4;
    const int m0 = blockIdx.y * 128, n0 = blockIdx.x * 128;
    const int mw = (wave & 1) * 64, nw = (wave >> 1) * 64;
    const int lr8 = lane >> 3, lc8 = lane & 7;

    float4v acc[4][4];
#pragma unroll
    for (int it = 0; it < 4; ++it)
#pragma unroll
        for (int nt = 0; nt < 4; ++nt) acc[it][nt] = (float4v){0.f, 0.f, 0.f, 0.f};

    for (int k0 = 0; k0 < DIMq; k0 += 64) {
        if (k0) __syncthreads();
#pragma unroll
        for (int i = 0; i < 4; ++i) {
            int issue = wave * 4 + i;
            int r = issue * 8 + lr8;            // tile row 0..127
            int c = lc8 ^ (r & 7);              // swizzled global chunk
            GL2LDS(A + (size_t)(m0 + r) * DIMq + k0 + c * 8, &As[issue * 512]);
            GL2LDS(W + (size_t)(n0 + r) * DIMq + k0 + c * 8, &Bs[issue * 512]);
        }
        __syncthreads();
#pragma unroll
        for (int kk = 0; kk < 2; ++kk) {
            short8 a[4], bfr[4];
#pragma unroll
            for (int it = 0; it < 4; ++it) {
                int r = mw + it * 16 + col;
                a[it] = *(const short8*)&As[r * 64 + (((kk * 4 + quad) ^ (r & 7)) * 8)];
            }
#pragma unroll
            for (int nt = 0; nt < 4; ++nt) {
                int r = nw + nt * 16 + col;
                bfr[nt] = *(const short8*)&Bs[r * 64 + (((kk * 4 + quad) ^ (r & 7)) * 8)];
            }
#pragma unroll
            for (int it = 0; it < 4; ++it)
#pragma unroll
                for (int nt = 0; nt < 4; ++nt)
                    acc[it][nt] = __builtin_amdgcn_mfma_f32_16x16x32_bf16(
                        a[it], bfr[nt], acc[it][nt], 0, 0, 0);
        }
    }

    if (mode == 0) {
#pragma unroll
        for (int it = 0; it < 4; ++it)
#pragma unroll
            for (int reg = 0; reg < 4; ++reg) {
                float* orow = OutF + (size_t)(m0 + mw + it * 16 + quad * 4 + reg) * DIMq
                            + n0 + nw + col;
#pragma unroll
                for (int nt = 0; nt < 4; ++nt) orow[nt * 16] = acc[it][nt][reg];
            }
    } else {
        const int mat = n0 / 768;                 // block-uniform (768%128==0)
        const int nbase = n0 - mat * 768 + nw;
#pragma unroll
        for (int it = 0; it < 4; ++it)
#pragma unroll
            for (int reg = 0; reg < 4; ++reg) {
                int m = m0 + mw + it * 16 + quad * 4 + reg;
                int bb = m >> 11, l = m & 2047;
#pragma unroll
                for (int nt = 0; nt < 4; ++nt) {
                    int nloc = nbase + nt * 16 + col;
                    int hh = nloc >> 6, c = nloc & 63;
                    size_t bh = (size_t)(bb * NHq + hh);
                    short v = f2bf(acc[it][nt][reg]);
                    if (mat == 0) {
                        Qg[(bh * Lq + l) * HDq + c] = v;
                    } else if (mat == 1) {
                        // K tile image: [bh][kt32][key32][hd-chunk swizzled]
                        Ktg[(bh * 64 + (l >> 5)) * 2048 + (l & 31) * 64
                            + (((c >> 3) ^ (l & 7)) * 8) + (c & 7)] = v;
                    } else {
                        // V^T tile image: [bh][kt32][hd][key-chunk swizzled]
                        Vtg[(bh * 64 + (l >> 5)) * 2048 + c * 32
                            + ((((l & 31) >> 3) + (c >> 1)) & 3) * 8 + (l & 7)] = v;
                    }
                }
            }
    }
}

// ---------------------------------------------------------------------------
// Flash attention: 64 q-rows/block, K-tiles of 32 keys, 64 iterations,
// SINGLE barrier per iteration.  K/V/bias double-buffered in LDS, filled by
// async global_load_lds (K/V tiles are straight memcpys of pre-swizzled
// global images).  P transform is intra-wave (lgkmcnt only).  Grid = 768
// blocks = exactly 3 resident/CU at 45 KB LDS.
// ---------------------------------------------------------------------------
__global__ __launch_bounds__(256, 3)
void attn_fwd2(const short* __restrict__ Qg, const short* __restrict__ Ktg,
               const short* __restrict__ Vtg, const float* __restrict__ pos_bias,
               const int* __restrict__ mask, short* __restrict__ AO)
{
    __shared__ __align__(16) short Ks[2][2048];   // [key32][hd64] swizzled
    __shared__ __align__(16) short Vt[2][2048];   // [hd64][key32] swizzled
    __shared__ __align__(16) float Bsh[2][2048];  // [qrow64][key32]
    __shared__ __align__(16) float mAll[Lq];      // 0 / -1e38 per key
    __shared__ __align__(16) short Ps[64][40];    // padded, b128-aligned rows

    const int qt = blockIdx.x, h = blockIdx.y, b = blockIdx.z;
    const int bh = b * NHq + h;
    const int tid = threadIdx.x;
    const int wave = tid >> 6, lane = tid & 63;
    const int col = lane & 15, quad = lane >> 4;
    const int lr8 = lane >> 3, lc8 = lane & 7;

    const short* Kb = Ktg + (size_t)bh * 64 * 2048;
    const short* Vb = Vtg + (size_t)bh * 64 * 2048;
    const float* Bb = pos_bias + (size_t)h * Lq * Lq + (size_t)(qt * 64) * Lq;
    const int* mk = mask + b * Lq;

    for (int i = tid; i < Lq; i += 256) mAll[i] = mk[i] ? 0.0f : -1e38f;

    const short* qrow = Qg + ((size_t)bh * Lq + qt * 64 + wave * 16 + col) * HDq;
    const short8 qa0 = *(const short8*)&qrow[quad * 8];
    const short8 qa1 = *(const short8*)&qrow[32 + quad * 8];

    auto stage = [&](int kt, int buf) {
        GL2LDS(Kb + (size_t)kt * 2048 + wave * 512 + lane * 8, &Ks[buf][wave * 512]);
        GL2LDS(Vb + (size_t)kt * 2048 + wave * 512 + lane * 8, &Vt[buf][wave * 512]);
#pragma unroll
        for (int j2 = 0; j2 < 2; ++j2) {
            int j = wave * 2 + j2;                       // bias rows j*8..j*8+8
            GL2LDS(Bb + (size_t)(j * 8 + lr8) * Lq + kt * 32 + lc8 * 4,
                   &Bsh[buf][j * 256]);
        }
    };

    stage(0, 0);

    float4v O[4];
    float m_run[4], l_run[4];
#pragma unroll
    for (int nt = 0; nt < 4; ++nt) O[nt] = (float4v){0.f, 0.f, 0.f, 0.f};
#pragma unroll
    for (int r = 0; r < 4; ++r) { m_run[r] = -1e37f; l_run[r] = 0.f; }

    __syncthreads();   // tile 0 + mask visible

    const int brow = wave * 16 + quad * 4;
    for (int kt = 0; kt < 64; ++kt) {
        const int cur = kt & 1;
        if (kt + 1 < 64) stage(kt + 1, cur ^ 1);   // async, drains at barrier

        // --- QK^T : S[16 x 32] per wave ---
        float4v S[2];
#pragma unroll
        for (int nt = 0; nt < 2; ++nt) {
            S[nt] = (float4v){0.f, 0.f, 0.f, 0.f};
            int key = nt * 16 + col;
            short8 kb0 = *(const short8*)&Ks[cur][key * 64 + ((quad ^ (key & 7)) * 8)];
            short8 kb1 = *(const short8*)&Ks[cur][key * 64 + (((4 + quad) ^ (key & 7)) * 8)];
            S[nt] = __builtin_amdgcn_mfma_f32_16x16x32_bf16(qa0, kb0, S[nt], 0, 0, 0);
            S[nt] = __builtin_amdgcn_mfma_f32_16x16x32_bf16(qa1, kb1, S[nt], 0, 0, 0);
        }

        // --- bias + mask + online softmax ---
        float sc[2][4];
#pragma unroll
        for (int nt = 0; nt < 2; ++nt) {
            float fm = mAll[kt * 32 + col + 16 * nt];
#pragma unroll
            for (int reg = 0; reg < 4; ++reg)
                sc[nt][reg] = S[nt][reg] + Bsh[cur][(brow + reg) * 32 + col + 16 * nt] + fm;
        }
        float tm[4], alpha[4], ps[4];
#pragma unroll
        for (int reg = 0; reg < 4; ++reg) {
            tm[reg] = fmaxf(sc[0][reg], sc[1][reg]);
#pragma unroll
            for (int off = 1; off < 16; off <<= 1)
                tm[reg] = fmaxf(tm[reg], __shfl_xor(tm[reg], off, 64));
            float mn = fmaxf(m_run[reg], tm[reg]);
            alpha[reg] = __expf(m_run[reg] - mn);
            m_run[reg] = mn;
            ps[reg] = 0.f;
        }
#pragma unroll
        for (int nt = 0; nt < 2; ++nt)
#pragma unroll
            for (int reg = 0; reg < 4; ++reg) {
                float p = __expf(sc[nt][reg] - m_run[reg]);
                sc[nt][reg] = p;
                ps[reg] += p;
            }
#pragma unroll
        for (int reg = 0; reg < 4; ++reg) {
#pragma unroll
            for (int off = 1; off < 16; off <<= 1)
                ps[reg] += __shfl_xor(ps[reg], off, 64);
            l_run[reg] = l_run[reg] * alpha[reg] + ps[reg];
        }
        // --- P -> LDS (intra-wave C->A transform) + O rescale ---
#pragma unroll
        for (int nt = 0; nt < 2; ++nt)
#pragma unroll
            for (int reg = 0; reg < 4; ++reg)
                Ps[brow + reg][col + 16 * nt] = f2bf(sc[nt][reg]);
#pragma unroll
        for (int nt = 0; nt < 4; ++nt)
#pragma unroll
            for (int reg = 0; reg < 4; ++reg)
                O[nt][reg] *= alpha[reg];
        asm volatile("s_waitcnt lgkmcnt(0)" ::: "memory");   // Ps writes done (wave-local)

        // --- PV : O[16 x 64hd] += P[16 x 32] @ V[32 x 64] ---
        short8 pa = *(const short8*)&Ps[wave * 16 + col][quad * 8];
#pragma unroll
        for (int nt = 0; nt < 4; ++nt) {
            int hd = nt * 16 + col;
            short8 vb = *(const short8*)&Vt[cur][hd * 32 + (((quad + (hd >> 1)) & 3) * 8)];
            O[nt] = __builtin_amdgcn_mfma_f32_16x16x32_bf16(pa, vb, O[nt], 0, 0, 0);
        }

        __syncthreads();   // single barrier: prefetch kt+1 landed, cur free
    }

    // --- epilogue: AO bf16 [B][L][DIM] ---
    short* aorow = AO + ((size_t)b * Lq + qt * 64 + brow) * DIMq + h * HDq + col;
#pragma unroll
    for (int reg = 0; reg < 4; ++reg) {
        float inv = 1.0f / l_run[reg];
#pragma unroll
        for (int nt = 0; nt < 4; ++nt)
            aorow[(size_t)reg * DIMq + 16 * nt] = f2bf(O[nt][reg] * inv);
    }
}

// ---------------------------------------------------------------------------
extern "C" void kernel_launch(void* const* d_in, const int* in_sizes, int n_in,
                              void* d_out, int out_size, void* d_ws, size_t ws_size,
                              hipStream_t stream) {
    const float* x        = (const float*)d_in[0];
    const float* pos_bias = (const float*)d_in[1];
    const float* Wq       = (const float*)d_in[2];
    const float* Wk       = (const float*)d_in[3];
    const float* Wv       = (const float*)d_in[4];
    const float* Wo       = (const float*)d_in[5];
    const int*   mask     = (const int*)d_in[6];
    float* out = (float*)d_out;

    const size_t nX = (size_t)Bq * Lq * DIMq;   // 3,145,728
    const size_t nW = (size_t)DIMq * DIMq;      //   589,824
    short* xb   = (short*)d_ws;
    short* wqkv = xb + nX;                      // wq|wk|wv contiguous (N=2304)
    short* wob  = wqkv + 3 * nW;
    short* Qg   = wob + nW;                     // [bh][l][hd]
    short* Ktg  = Qg + nX;                      // pre-swizzled K tiles
    short* Vtg  = Ktg + nX;                     // pre-swizzled V^T tiles
    short* AOb  = Vtg + nX;                     // [B][L][DIM] bf16

    dim3 blk(256);
    hipLaunchKernelGGL(to_bf16, dim3(1344), blk, 0, stream,
                       x, Wq, Wk, Wv, Wo, xb, wqkv, wqkv + nW, wqkv + 2 * nW, wob);

    // fused QKV: [4096 x 2304] = xb @ wqkv^T, scatter to Qg/Ktg/Vtg
    hipLaunchKernelGGL(gemm128, dim3(2304 / 128, (Bq * Lq) / 128), blk, 0, stream,
                       xb, wqkv, Qg, Ktg, Vtg, (float*)nullptr, 1);

    hipLaunchKernelGGL(attn_fwd2, dim3(Lq / 64, NHq, Bq), blk, 0, stream,
                       Qg, Ktg, Vtg, pos_bias, mask, AOb);

    // output projection, fp32 out
    hipLaunchKernelGGL(gemm128, dim3(DIMq / 128, (Bq * Lq) / 128), blk, 0, stream,
                       AOb, wob, (short*)nullptr, (short*)nullptr,
                       (short*)nullptr, out, 0);
}